// Round 5
// baseline (631.279 us; speedup 1.0000x reference)
//
#include <hip/hip_runtime.h>
#include <hip/hip_bf16.h>
#include <stdint.h>

#define BDIM 4
#define SDIM 1024
#define DDIM 1024
#define HDIM 16
#define DHDIM 64

typedef __bf16 bf16_t;
typedef __bf16 bf16x8 __attribute__((ext_vector_type(8)));
typedef __bf16 bf16x4 __attribute__((ext_vector_type(4)));
typedef float f32x4 __attribute__((ext_vector_type(4)));

typedef __attribute__((address_space(3))) uint32_t lds_u32;
typedef const __attribute__((address_space(1))) uint32_t glb_u32;

__device__ __forceinline__ void glds16(const void* g, void* l) {
    __builtin_amdgcn_global_load_lds((glb_u32*)g, (lds_u32*)l, 16, 0, 0);
}

// ---------------- conversions ----------------

__global__ __launch_bounds__(256) void convert_x_kernel(const float* __restrict__ X,
                                                        bf16_t* __restrict__ Xb, int n) {
    int i = (blockIdx.x * 256 + threadIdx.x) * 4;
    if (i >= n) return;
    float4 v = *(const float4*)(X + i);
    bf16x4 o;
    o[0] = (bf16_t)v.x; o[1] = (bf16_t)v.y; o[2] = (bf16_t)v.z; o[3] = (bf16_t)v.w;
    *(bf16x4*)(Xb + i) = o;
}

// W[k][n] fp32 -> Wt[n][k] bf16, for 4 weights (z selects)
__global__ __launch_bounds__(256) void transpose_w_kernel(const float* __restrict__ W0,
                                                          const float* __restrict__ W1,
                                                          const float* __restrict__ W2,
                                                          const float* __restrict__ W3,
                                                          bf16_t* __restrict__ Wt) {
    __shared__ float tile[32][33];
    int z = blockIdx.z;
    const float* W = (z == 0) ? W0 : (z == 1) ? W1 : (z == 2) ? W2 : W3;
    bf16_t* dst = Wt + (size_t)z * DDIM * DDIM;
    int bx = blockIdx.x * 32;  // n tile
    int by = blockIdx.y * 32;  // k tile
    int x = threadIdx.x & 31, y0 = threadIdx.x >> 5;
#pragma unroll
    for (int i = 0; i < 4; i++) {
        int y = y0 + i * 8;
        tile[y][x] = W[(size_t)(by + y) * DDIM + bx + x];
    }
    __syncthreads();
#pragma unroll
    for (int i = 0; i < 4; i++) {
        int y = y0 + i * 8;
        dst[(size_t)(bx + y) * DDIM + by + x] = (bf16_t)tile[x][y];
    }
}

// Detect mask element layout: uint8 bools -> bytes at i%4!=0 nonzero somewhere;
// int32 -> those bytes all 0. flag=1 means stride 1 (uint8), else stride 4.
__global__ __launch_bounds__(1024) void mask_flag_kernel(const unsigned char* __restrict__ mb,
                                                         int* __restrict__ flag) {
    __shared__ int any;
    if (threadIdx.x == 0) any = 0;
    __syncthreads();
    int loc = 0;
    for (int i = threadIdx.x; i < BDIM * SDIM; i += 1024)
        if ((i & 3) && mb[i]) loc = 1;
    if (loc) any = 1;
    __syncthreads();
    if (threadIdx.x == 0) *flag = any ? 1 : 0;
}

// ---------------- bias transpose + mask fuse ----------------
// inter[b][q][k][h] fp32 -> biasT[b*16+h][q][k] bf16, minus 1e9 where mask[b][k]==0
__global__ __launch_bounds__(256) void bias_tr_kernel(const float* __restrict__ inter,
                                                      const unsigned char* __restrict__ maskb,
                                                      const int* __restrict__ flagp,
                                                      bf16_t* __restrict__ biasT) {
    constexpr int QS = 72;            // q stride (bf16 elements)
    constexpr int HS = 16 * 72 + 8;   // h stride = 1160 (breaks pow2 banking)
    __shared__ bf16_t tile[16 * HS];  // ~37 KB
    __shared__ float pen[64];
    const int k0 = blockIdx.x * 64;
    const int q0 = blockIdx.y * 16;
    const int b  = blockIdx.z;
    const int t = threadIdx.x;
    const int mstride = (*flagp) ? 1 : 4;
    if (t < 64)
        pen[t] = maskb[((size_t)b * SDIM + k0 + t) * mstride] ? 0.f : 1.0e9f;

    // read 16 q-rows x (64 k x 16 h) floats, coalesced
    const float* src = inter + (((size_t)b * SDIM + q0) * SDIM + k0) * HDIM;
    const int k = t >> 2, h = (t & 3) * 4;   // within a row: rem = t*4 = k*16+h
#pragma unroll
    for (int q = 0; q < 16; q++) {
        float4 v = *(const float4*)(src + (size_t)q * SDIM * HDIM + t * 4);
        tile[(h + 0) * HS + q * QS + k] = (bf16_t)v.x;
        tile[(h + 1) * HS + q * QS + k] = (bf16_t)v.y;
        tile[(h + 2) * HS + q * QS + k] = (bf16_t)v.z;
        tile[(h + 3) * HS + q * QS + k] = (bf16_t)v.w;
    }
    __syncthreads();
    // write out: 256 rows (h,q) x 64 k bf16 (128 B rows, 8 lanes x 16 B)
#pragma unroll
    for (int p = 0; p < 8; p++) {
        int row = p * 32 + (t >> 3);
        int hh = row >> 4, qq = row & 15;
        int kc = (t & 7) * 8;
        bf16x8 vv = *(const bf16x8*)(tile + hh * HS + qq * QS + kc);
        bf16x8 ov;
#pragma unroll
        for (int u = 0; u < 8; u++) ov[u] = (bf16_t)((float)vv[u] - pen[kc + u]);
        *(bf16x8*)(biasT + ((size_t)(b * HDIM + hh) * SDIM + q0 + qq) * SDIM + k0 + kc) = ov;
    }
}

// ---------------- GEMM: C[m,n] = sum_k A[m,k] * Bt[n,k] (m97-style) ----------------
// MODE 0: write Q bf16 [B,H,S,DH] (scaled 0.125), K bf16 [B,H,S,DH], V TRANSPOSED
//         as Vt [B,H,DH,S]. N=3072.
// MODE 1: write fp32 C row-major [M,1024]
template <int MODE>
__global__ __launch_bounds__(256) void gemm_bt_kernel(const bf16_t* __restrict__ A,
                                                      const bf16_t* __restrict__ Bt,
                                                      bf16_t* __restrict__ Qo, bf16_t* __restrict__ Ko,
                                                      bf16_t* __restrict__ Vto, float* __restrict__ Co) {
    __shared__ bf16_t As[128 * 32];
    __shared__ bf16_t Bs[128 * 32];
    const int m0 = blockIdx.x * 128;
    const int n0 = blockIdx.y * 128;
    const int t = threadIdx.x;
    const int lane = t & 63, w = t >> 6;
    const int wm = w & 1, wn = w >> 1;
    const int low = lane & 15, quad = lane >> 4;
    f32x4 acc[4][4] = {};

    const int srow = w * 16 + (lane >> 2);
    const int koff = (lane & 3) * 8;
    const bf16_t* Ag = A + (size_t)(m0 + srow) * DDIM + koff;
    const bf16_t* Bg = Bt + (size_t)(n0 + srow) * DDIM + koff;
    bf16_t* AsW = As + w * 512;
    bf16_t* BsW = Bs + w * 512;

    for (int k0 = 0; k0 < DDIM; k0 += 32) {
        __syncthreads();
        glds16(Ag + k0, AsW);
        glds16(Ag + (size_t)64 * DDIM + k0, AsW + 64 * 32);
        glds16(Bg + k0, BsW);
        glds16(Bg + (size_t)64 * DDIM + k0, BsW + 64 * 32);
        __syncthreads();
        bf16x8 af[4], bv[4];
#pragma unroll
        for (int mt = 0; mt < 4; mt++)
            af[mt] = *(const bf16x8*)(As + (wm * 64 + mt * 16 + low) * 32 + quad * 8);
#pragma unroll
        for (int nt = 0; nt < 4; nt++)
            bv[nt] = *(const bf16x8*)(Bs + (wn * 64 + nt * 16 + low) * 32 + quad * 8);
#pragma unroll
        for (int mt = 0; mt < 4; mt++)
#pragma unroll
            for (int nt = 0; nt < 4; nt++)
                acc[mt][nt] = __builtin_amdgcn_mfma_f32_16x16x32_bf16(af[mt], bv[nt], acc[mt][nt], 0, 0, 0);
    }

#pragma unroll
    for (int mt = 0; mt < 4; mt++) {
#pragma unroll
        for (int nt = 0; nt < 4; nt++) {
#pragma unroll
            for (int r = 0; r < 4; r++) {
                int mrow = m0 + wm * 64 + mt * 16 + quad * 4 + r;
                int ncol = n0 + wn * 64 + nt * 16 + low;
                float vv = acc[mt][nt][r];
                if (MODE == 0) {
                    int which = ncol >> 10, nl = ncol & 1023;
                    int h = nl >> 6, dh = nl & 63;
                    int b = mrow >> 10, s = mrow & 1023;
                    if (which == 0)
                        Qo[((size_t)(b * HDIM + h) * SDIM + s) * DHDIM + dh] = (bf16_t)(vv * 0.125f);
                    else if (which == 1)
                        Ko[((size_t)(b * HDIM + h) * SDIM + s) * DHDIM + dh] = (bf16_t)vv;
                    else  // V transposed: Vt[b,h][dh][s]
                        Vto[((size_t)(b * HDIM + h) * DHDIM + dh) * SDIM + s] = (bf16_t)vv;
                } else {
                    Co[(size_t)mrow * DDIM + ncol] = vv;
                }
            }
        }
    }
}

// ---------------- fused attention: barrier-free, 1 wave = 1 (b,h,q-tile) ----
// grid (BH=64, S/64=16); block 256 = 4 waves; wave w owns q-tile blockIdx.y*4+w.
// Raw fp32 scores C->A via wave-private LDS; softmax in A-layout (rows on `low`
// lanes): bias loads contiguous from biasT, 2 shuffles per chunk, row-sum
// deferred per-lane. P converts directly to A-frags (no P round-trip).
__global__ __launch_bounds__(256, 4) void attn_kernel(const bf16_t* __restrict__ Q,
                                                      const bf16_t* __restrict__ K,
                                                      const bf16_t* __restrict__ Vt,
                                                      const bf16_t* __restrict__ biasT,
                                                      bf16_t* __restrict__ hid) {
    constexpr int KSp = 66;  // S-tile row stride (fp32): 2low+8quad banking ~uniform
    __shared__ float Sl[4][16 * KSp];  // 16.9 KB total
    const int bh = blockIdx.x;
    const int b = bh >> 4, h = bh & 15;
    const int t = threadIdx.x;
    const int w = t >> 6, lane = t & 63;
    const int low = lane & 15, quad = lane >> 4;
    const int q0 = (blockIdx.y * 4 + w) * 16;

    const bf16_t* Qb = Q + ((size_t)bh * SDIM + q0) * DHDIM;
    const bf16_t* Kb = K + (size_t)bh * SDIM * DHDIM;
    const bf16_t* VtB = Vt + (size_t)bh * DHDIM * SDIM;
    const bf16_t* biasB = biasT + ((size_t)bh * SDIM + q0 + low) * SDIM;  // row q0+low
    float* Sw = &Sl[w][0];

    bf16x8 qf0 = *(const bf16x8*)(Qb + low * DHDIM + quad * 8);
    bf16x8 qf1 = *(const bf16x8*)(Qb + low * DHDIM + 32 + quad * 8);

    float mrow = -3.0e38f;  // running max for row q0+low
    float lpart = 0.f;      // per-lane partial sum for row q0+low
    f32x4 accO[4] = {};

    for (int c = 0; c < SDIM / 64; c++) {
        const int kbase = c * 64;
        // bias for row q0+low, cols kbase + quad*8 + {0..7, 32..39}
        bf16x8 bb0 = *(const bf16x8*)(biasB + kbase + quad * 8);
        bf16x8 bb1 = *(const bf16x8*)(biasB + kbase + 32 + quad * 8);
        // ---- S = Q K^T (C-layout) ----
        f32x4 sacc[4];
#pragma unroll
        for (int nt = 0; nt < 4; nt++) {
            const bf16_t* kp = Kb + (size_t)(kbase + nt * 16 + low) * DHDIM;
            bf16x8 kf0 = *(const bf16x8*)(kp + quad * 8);
            bf16x8 kf1 = *(const bf16x8*)(kp + 32 + quad * 8);
            f32x4 z = {};
            z = __builtin_amdgcn_mfma_f32_16x16x32_bf16(qf0, kf0, z, 0, 0, 0);
            z = __builtin_amdgcn_mfma_f32_16x16x32_bf16(qf1, kf1, z, 0, 0, 0);
            sacc[nt] = z;
        }
        // ---- C-layout -> LDS (wave-private, wave-ordered DS ops) ----
#pragma unroll
        for (int nt = 0; nt < 4; nt++)
#pragma unroll
            for (int r = 0; r < 4; r++)
                Sw[(quad * 4 + r) * KSp + nt * 16 + low] = sacc[nt][r];
        // ---- A-layout read: row q0+low, k = s*32 + quad*8 + j ----
        float4 a0 = *(const float4*)(Sw + low * KSp + quad * 8);
        float4 a1 = *(const float4*)(Sw + low * KSp + quad * 8 + 4);
        float4 a2 = *(const float4*)(Sw + low * KSp + 32 + quad * 8);
        float4 a3 = *(const float4*)(Sw + low * KSp + 32 + quad * 8 + 4);
        float sj[16];
        sj[0] = a0.x + (float)bb0[0]; sj[1] = a0.y + (float)bb0[1];
        sj[2] = a0.z + (float)bb0[2]; sj[3] = a0.w + (float)bb0[3];
        sj[4] = a1.x + (float)bb0[4]; sj[5] = a1.y + (float)bb0[5];
        sj[6] = a1.z + (float)bb0[6]; sj[7] = a1.w + (float)bb0[7];
        sj[8] = a2.x + (float)bb1[0]; sj[9] = a2.y + (float)bb1[1];
        sj[10] = a2.z + (float)bb1[2]; sj[11] = a2.w + (float)bb1[3];
        sj[12] = a3.x + (float)bb1[4]; sj[13] = a3.y + (float)bb1[5];
        sj[14] = a3.z + (float)bb1[6]; sj[15] = a3.w + (float)bb1[7];
        // ---- softmax, A-layout (row on `low` lanes, spread over quads) ----
        float mx = sj[0];
#pragma unroll
        for (int j = 1; j < 16; j++) mx = fmaxf(mx, sj[j]);
        mx = fmaxf(mx, __shfl_xor(mx, 16));
        mx = fmaxf(mx, __shfl_xor(mx, 32));
        float mn = fmaxf(mrow, mx);
        float alpha = __expf(mrow - mn);
        mrow = mn;
        lpart *= alpha;
        float ss = 0.f;
#pragma unroll
        for (int j = 0; j < 16; j++) {
            float p = __expf(sj[j] - mn);
            sj[j] = p;
            ss += p;
        }
        lpart += ss;
        // alpha for accO rows quad*4+r (held by lanes with low == that row)
        float ar[4];
#pragma unroll
        for (int r = 0; r < 4; r++) ar[r] = __shfl(alpha, (lane & 48) + quad * 4 + r);
#pragma unroll
        for (int nt = 0; nt < 4; nt++)
#pragma unroll
            for (int r = 0; r < 4; r++) accO[nt][r] *= ar[r];
        // ---- P A-frags directly from registers ----
        bf16x8 pf0, pf1;
#pragma unroll
        for (int j = 0; j < 8; j++) { pf0[j] = (bf16_t)sj[j]; pf1[j] = (bf16_t)sj[8 + j]; }
        // ---- O += P V ----
#pragma unroll
        for (int nt = 0; nt < 4; nt++) {
            const bf16_t* vp = VtB + (size_t)(nt * 16 + low) * SDIM + kbase;
            bf16x8 vf0 = *(const bf16x8*)(vp + quad * 8);
            bf16x8 vf1 = *(const bf16x8*)(vp + 32 + quad * 8);
            accO[nt] = __builtin_amdgcn_mfma_f32_16x16x32_bf16(pf0, vf0, accO[nt], 0, 0, 0);
            accO[nt] = __builtin_amdgcn_mfma_f32_16x16x32_bf16(pf1, vf1, accO[nt], 0, 0, 0);
        }
    }
    // final row sums (rows on low lanes) -> redistribute to C-layout rows
    lpart += __shfl_xor(lpart, 16);
    lpart += __shfl_xor(lpart, 32);
    float lr[4];
#pragma unroll
    for (int r = 0; r < 4; r++) lr[r] = __shfl(lpart, (lane & 48) + quad * 4 + r);
    // epilogue: hidden[b, q, h*64+dh] bf16
#pragma unroll
    for (int r = 0; r < 4; r++) {
        float inv = 1.f / lr[r];
#pragma unroll
        for (int nt = 0; nt < 4; nt++) {
            hid[((size_t)b * SDIM + q0 + quad * 4 + r) * DDIM + h * 64 + nt * 16 + low] =
                (bf16_t)(accO[nt][r] * inv);
        }
    }
}

// ---------------- launcher ----------------

extern "C" void kernel_launch(void* const* d_in, const int* in_sizes, int n_in,
                              void* d_out, int out_size, void* d_ws, size_t ws_size,
                              hipStream_t stream) {
    const float* X = (const float*)d_in[0];
    const unsigned char* maskb = (const unsigned char*)d_in[1];
    const float* inter = (const float*)d_in[2];
    const float* WQ = (const float*)d_in[3];
    const float* WK = (const float*)d_in[4];
    const float* WV = (const float*)d_in[5];
    const float* WO = (const float*)d_in[6];
    float* out = (float*)d_out;

    char* ws = (char*)d_ws;
    const size_t MB = 1024 * 1024;
    bf16_t* Xb    = (bf16_t*)(ws + 0 * MB);
    bf16_t* Wt    = (bf16_t*)(ws + 8 * MB);    // [4][1024][1024] bf16 transposed
    bf16_t* Qm    = (bf16_t*)(ws + 16 * MB);   // [B,H,S,DH]
    bf16_t* Km    = (bf16_t*)(ws + 24 * MB);   // [B,H,S,DH]
    bf16_t* Vtm   = (bf16_t*)(ws + 32 * MB);   // [B,H,DH,S]
    bf16_t* hid   = (bf16_t*)(ws + 40 * MB);   // [B,S,D] bf16
    int* flag     = (int*)(ws + 48 * MB);
    bf16_t* biasT = (bf16_t*)(ws + 64 * MB);   // [B*H][S][S] bf16, 128 MB

    convert_x_kernel<<<BDIM * SDIM * DDIM / (256 * 4), 256, 0, stream>>>(X, Xb, BDIM * SDIM * DDIM);
    transpose_w_kernel<<<dim3(32, 32, 4), 256, 0, stream>>>(WQ, WK, WV, WO, Wt);
    mask_flag_kernel<<<1, 1024, 0, stream>>>(maskb, flag);
    bias_tr_kernel<<<dim3(16, 64, 4), 256, 0, stream>>>(inter, maskb, flag, biasT);
    // QKV projection: M=4096, N=3072 (Wt_Q|Wt_K|Wt_V contiguous)
    gemm_bt_kernel<0><<<dim3(32, 24), 256, 0, stream>>>(Xb, Wt, Qm, Km, Vtm, nullptr);
    // barrier-free attention; same-bh blocks map to the same XCD (64 % 8 == 0)
    attn_kernel<<<dim3(BDIM * HDIM, SDIM / 64), 256, 0, stream>>>(Qm, Km, Vtm, biasT, hid);
    // output projection: M=4096, N=1024
    gemm_bt_kernel<1><<<dim3(32, 8), 256, 0, stream>>>(hid, Wt + (size_t)3 * DDIM * DDIM,
                                                       nullptr, nullptr, nullptr, out);
}